// Round 10
// baseline (2306.681 us; speedup 1.0000x reference)
//
#include <hip/hip_runtime.h>
#include <math.h>

#define LN_EPS 1e-5f

typedef short s8v __attribute__((ext_vector_type(8)));
typedef float f4v __attribute__((ext_vector_type(4)));

__device__ __forceinline__ short f2bf(float x) {
  union { float f; unsigned u; } v; v.f = x;
  const unsigned r = v.u + 0x7fffu + ((v.u >> 16) & 1u);
  return (short)(r >> 16);
}
__device__ __forceinline__ float bf2f(short s) {
  union { unsigned u; float f; } v;
  v.u = ((unsigned)(unsigned short)s) << 16;
  return v.f;
}

__device__ __forceinline__ void gld16(const void* g, void* l) {
  __builtin_amdgcn_global_load_lds(
      (const __attribute__((address_space(1))) void*)g,
      (__attribute__((address_space(3))) void*)l, 16, 0, 0);
}

enum { EP_SPLIT = 0, EP_SPLIT_T, EP_SIG, EP_RES, EP_BIAS, EP_ACC, EP_ACCGELU };

// Split-bf16 NT GEMM: C = A * B^T, A[M][K], B[N][K], both given as hi/lo bf16.
// 3-term MFMA (hi*hi + hi*lo + lo*hi) ~= fp32 precision.
// Tile: BM=64*MW rows x BN=64*WC cols, BK=64. waves = MW*WC; each wave owns a
// 64x64 sub-tile (wr=wave/WC rows, wc=wave%WC cols) -> fragment/epilogue code
// is IDENTICAL for all MW/WC (m89-verified layout untouched). MW=1 doubles
// blocks/launch vs the old BM=128 (R4: 9-12% occupancy, latency-bound; this
// is the occupancy fix).
// XOR(row&7) chunk16 bank-swizzle on the global SOURCE during global_load_lds
// (linear LDS dest) and the same involution on ds_read -> conflict-free.
// 1D grid, XCD-bijective chunking (nwg%8==0 for every launch), panel-major:
// l -> pn (fastest), pm, zb -> same-A-panel blocks contiguous in one XCD chunk.
template <int EP, int WC, int MW>
__global__ __launch_bounds__(64 * MW * WC) void gemmk(
    const short* __restrict__ Ah, const short* __restrict__ Al,
    const short* __restrict__ Bh, const short* __restrict__ Bl,
    short* __restrict__ Ch, short* __restrict__ Cl, float* __restrict__ Cf,
    const float* __restrict__ bias, const short* __restrict__ resH,
    const short* __restrict__ resL, float* __restrict__ out2, int pnCnt,
    int pmCnt, int lda, int ldb, int ldc, int K, long sA, long sB, long sC,
    float scale) {
  constexpr int BM = 64 * MW, BN = 64 * WC, T = 64 * MW * WC;
  constexpr int RA = (BM * 128) / (T * 16);  // 16B rounds per A tensor
  constexpr int RB = (BN * 128) / (T * 16);
  __shared__ short lds[(2 * BM + 2 * BN) * 64];
  short* AsH = lds;
  short* AsL = lds + BM * 64;
  short* BsH = lds + 2 * BM * 64;
  short* BsL = lds + 2 * BM * 64 + BN * 64;

  const int tid = threadIdx.x;
  const int lane = tid & 63;
  const int wave = tid >> 6;
  const int wr = wave / WC;       // 0..MW-1
  const int wc = wave % WC;       // 0..WC-1
  const int half = lane >> 4;     // 0..3
  const int l15 = lane & 15;

  // --- XCD-chunked panel-major block decode ---
  const int chunk = gridDim.x >> 3;
  const int l = ((int)blockIdx.x & 7) * chunk + ((int)blockIdx.x >> 3);
  const int pn = l % pnCnt;
  const int t1 = l / pnCnt;
  const int pm = t1 % pmCnt;
  const long zb = t1 / pmCnt;
  const int bm = pm * BM;
  const int bn = pn * BN;

  Ah += zb * sA; Al += zb * sA;
  Bh += zb * sB; Bl += zb * sB;

  f4v acc[4][4];
#pragma unroll
  for (int i = 0; i < 4; ++i)
#pragma unroll
    for (int j = 0; j < 4; ++j)
#pragma unroll
      for (int r = 0; r < 4; ++r) acc[i][j][r] = 0.f;

  for (int k0 = 0; k0 < K; k0 += 64) {
    __syncthreads();  // protect LDS from previous iteration's readers
#pragma unroll
    for (int t = 0; t < RA; ++t) {
      const int off = (t * T + tid) * 16;  // byte offset in [BM][128B] tile
      const int row = off >> 7;
      const int ke = ((((off >> 4) & 7) ^ (row & 7)) << 3);  // swizzled k-chunk
      const long ga = (long)(bm + row) * lda + k0 + ke;
      gld16(Ah + ga, (char*)AsH + off);
      gld16(Al + ga, (char*)AsL + off);
    }
#pragma unroll
    for (int t = 0; t < RB; ++t) {
      const int off = (t * T + tid) * 16;
      const int row = off >> 7;
      const int ke = ((((off >> 4) & 7) ^ (row & 7)) << 3);
      const long gb = (long)(bn + row) * ldb + k0 + ke;
      gld16(Bh + gb, (char*)BsH + off);
      gld16(Bl + gb, (char*)BsL + off);
    }
    __syncthreads();

#pragma unroll
    for (int s = 0; s < 2; ++s) {
      s8v ah[4], al[4], bh[4], bl[4];
#pragma unroll
      for (int i = 0; i < 4; ++i) {
        const int r = wr * 64 + i * 16 + l15;
        const int ad = r * 64 + ((((s << 2) + half) ^ (r & 7)) << 3);
        ah[i] = *(const s8v*)&AsH[ad];
        al[i] = *(const s8v*)&AsL[ad];
      }
#pragma unroll
      for (int j = 0; j < 4; ++j) {
        const int c = wc * 64 + j * 16 + l15;
        const int bd = c * 64 + ((((s << 2) + half) ^ (c & 7)) << 3);
        bh[j] = *(const s8v*)&BsH[bd];
        bl[j] = *(const s8v*)&BsL[bd];
      }
#pragma unroll
      for (int i = 0; i < 4; ++i)
#pragma unroll
        for (int j = 0; j < 4; ++j) {
          acc[i][j] = __builtin_amdgcn_mfma_f32_16x16x32_bf16(ah[i], bh[j],
                                                              acc[i][j], 0, 0, 0);
          acc[i][j] = __builtin_amdgcn_mfma_f32_16x16x32_bf16(ah[i], bl[j],
                                                              acc[i][j], 0, 0, 0);
          acc[i][j] = __builtin_amdgcn_mfma_f32_16x16x32_bf16(al[i], bh[j],
                                                              acc[i][j], 0, 0, 0);
        }
    }
  }

  // Epilogue. D frag: col = lane&15, row = (lane>>4)*4 + reg (m89-verified).
#pragma unroll
  for (int i = 0; i < 4; ++i) {
#pragma unroll
    for (int r = 0; r < 4; ++r) {
      const int row = bm + wr * 64 + i * 16 + half * 4 + r;
#pragma unroll
      for (int j = 0; j < 4; ++j) {
        const int col = bn + wc * 64 + j * 16 + l15;
        float x = acc[i][j][r];
        if (EP == EP_SPLIT) {
          const long idx = zb * sC + (long)row * ldc + col;
          const short h = f2bf(x);
          Ch[idx] = h;
          Cl[idx] = f2bf(x - bf2f(h));
        } else if (EP == EP_SPLIT_T) {
          // v-projection: write transposed vt[b][col][tok], row = b*1024+tok
          const long idx = ((long)(row >> 10) * 576 + col) * 1024 + (row & 1023);
          const short h = f2bf(x);
          Ch[idx] = h;
          Cl[idx] = f2bf(x - bf2f(h));
        } else if (EP == EP_SIG) {
          x = 1.f / (1.f + expf(-x * scale));
          const long idx = zb * sC + (long)row * ldc + col;
          const short h = f2bf(x);
          Ch[idx] = h;
          Cl[idx] = f2bf(x - bf2f(h));
        } else if (EP == EP_RES) {
          const long idx = (long)row * ldc + col;
          Cf[idx] = x + bias[col] + bf2f(resH[idx]) + bf2f(resL[idx]);
        } else if (EP == EP_BIAS) {
          const long idx = (long)row * ldc + col;
          Cf[idx] = x + bias[col];
        } else if (EP == EP_ACC) {
          const long idx = (long)row * ldc + col;
          Cf[idx] += x;
        } else if (EP == EP_ACCGELU) {
          const long idx = (long)row * ldc + col;
          const float sum = Cf[idx] + x;
          out2[idx] = 0.5f * sum * (1.f + erff(sum * 0.70710678118654752f));
        }
      }
    }
  }
}

// LayerNorm over C=576, writes hi/lo bf16 split. One 576-thread block per row.
__global__ __launch_bounds__(576) void ln576(const float* __restrict__ x,
                                             const float* __restrict__ g,
                                             const float* __restrict__ b,
                                             short* __restrict__ oh,
                                             short* __restrict__ ol) {
  __shared__ float red[2][9];
  __shared__ float mu_s, rs_s;
  const long row = blockIdx.x;
  const int t = threadIdx.x;
  const float v = x[row * 576 + t];
  float s = v, s2 = v * v;
#pragma unroll
  for (int off = 32; off > 0; off >>= 1) {
    s += __shfl_xor(s, off);
    s2 += __shfl_xor(s2, off);
  }
  if ((t & 63) == 0) {
    red[0][t >> 6] = s;
    red[1][t >> 6] = s2;
  }
  __syncthreads();
  if (t == 0) {
    float a = 0.f, a2 = 0.f;
#pragma unroll
    for (int i = 0; i < 9; ++i) {
      a += red[0][i];
      a2 += red[1][i];
    }
    const float mu = a * (1.f / 576.f);
    mu_s = mu;
    rs_s = rsqrtf(a2 * (1.f / 576.f) - mu * mu + LN_EPS);
  }
  __syncthreads();
  const float y = (v - mu_s) * rs_s * g[t] + b[t];
  const short h = f2bf(y);
  oh[row * 576 + t] = h;
  ol[row * 576 + t] = f2bf(y - bf2f(h));
}

// fp32 -> (hi,lo) bf16 split, elementwise.
__global__ __launch_bounds__(256) void splitk(const float* __restrict__ in,
                                              short* __restrict__ oh,
                                              short* __restrict__ ol, long n) {
  long i = (long)blockIdx.x * blockDim.x + threadIdx.x;
  const long stride = (long)gridDim.x * blockDim.x;
  for (; i < n; i += stride) {
    const float x = in[i];
    const short h = f2bf(x);
    oh[i] = h;
    ol[i] = f2bf(x - bf2f(h));
  }
}

extern "C" void kernel_launch(void* const* d_in, const int* in_sizes, int n_in,
                              void* d_out, int out_size, void* d_ws,
                              size_t ws_size, hipStream_t stream) {
  const float* img = (const float*)d_in[0];
  const float* aolp = (const float*)d_in[1];
  const float* dolp = (const float*)d_in[2];
  const float* lnx_g = (const float*)d_in[3];
  const float* lnx_b = (const float*)d_in[4];
  const float* lny_g = (const float*)d_in[5];
  const float* lny_b = (const float*)d_in[6];
  const float* lnz_g = (const float*)d_in[7];
  const float* lnz_b = (const float*)d_in[8];
  const float* Wq = (const float*)d_in[9];
  const float* Wk = (const float*)d_in[10];
  const float* Wv = (const float*)d_in[11];
  const float* Wp = (const float*)d_in[12];
  const float* bp = (const float*)d_in[13];
  const float* Wf = (const float*)d_in[14];
  const float* bf = (const float*)d_in[15];
  float* out = (float*)d_out;

  const long S = 8L * 1024 * 576;   // 4,718,592
  const long W = 6L * 576 * 576;    // 1,990,656 (also == 576*3456)
  char* p = (char*)d_ws;
  auto alloc = [&](long bytes) {
    char* r = p;
    p += (bytes + 255) & ~255L;
    return r;
  };
  short* xn_h = (short*)alloc(S * 2);
  short* xn_l = (short*)alloc(S * 2);
  short* yn_h = (short*)alloc(S * 2);  // also o after AV
  short* yn_l = (short*)alloc(S * 2);
  short* q_h = (short*)alloc(S * 2);   // also z after LNz
  short* q_l = (short*)alloc(S * 2);
  short* k_h = (short*)alloc(S * 2);
  short* k_l = (short*)alloc(S * 2);
  short* vt_h = (short*)alloc(S * 2);  // [8][576][1024]
  short* vt_l = (short*)alloc(S * 2);
  short* attn_h = (short*)alloc(8L * 1024 * 1024 * 2 * 2);  // hi then lo
  short* attn_l = attn_h + 8L * 1024 * 1024;
  float* t_f32 = (float*)attn_h;  // aliases attn (dead after AV); 18.9<=33.5MB
  float* fused = (float*)alloc(S * 4);
  short* wq_h = (short*)alloc(W * 2);
  short* wq_l = (short*)alloc(W * 2);
  short* wk_h = (short*)alloc(W * 2);
  short* wk_l = (short*)alloc(W * 2);
  short* wv_h = (short*)alloc(W * 2);
  short* wv_l = (short*)alloc(W * 2);
  short* wp_h = (short*)alloc(W * 2);
  short* wp_l = (short*)alloc(W * 2);
  short* wf_h = (short*)alloc(W * 2);
  short* wf_l = (short*)alloc(W * 2);

  // weight splits (re-done every call; ws is re-poisoned)
  splitk<<<1024, 256, 0, stream>>>(Wq, wq_h, wq_l, W);
  splitk<<<1024, 256, 0, stream>>>(Wk, wk_h, wk_l, W);
  splitk<<<1024, 256, 0, stream>>>(Wv, wv_h, wv_l, W);
  splitk<<<1024, 256, 0, stream>>>(Wp, wp_h, wp_l, W);
  splitk<<<1024, 256, 0, stream>>>(Wf, wf_h, wf_l, W);

  const float* src[3] = {img, aolp, dolp};
  const int xi[6] = {0, 0, 1, 1, 2, 2};
  const int yi[6] = {1, 2, 0, 2, 0, 1};
  const float scale = 1.f / 24.f;  // 576^-0.5

  // 1D grids (all multiples of 8 -> bijective XCD chunking). MW=1 tiles:
  const int nProj = 9 * 128;      // pn=9 (N=576/64), pm=128 (M=8192/64) -> 1152
  const int nScore = 8 * 16 * 8;  // pn=8 (1024/128), pm=16 (1024/64), b=8 -> 1024
  const int nAV = 9 * 16 * 8;     // pn=9, pm=16, b=8 -> 1152

  for (int z = 0; z < 6; ++z) {
    const long wo = (long)z * 576 * 576;
    ln576<<<8192, 576, 0, stream>>>(src[xi[z]], lnx_g + z * 576,
                                    lnx_b + z * 576, xn_h, xn_l);
    ln576<<<8192, 576, 0, stream>>>(src[yi[z]], lny_g + z * 576,
                                    lny_b + z * 576, yn_h, yn_l);
    // q = LN(y) @ Wq^T   k = LN(x) @ Wk^T   vt = (LN(x) @ Wv^T)^T
    gemmk<EP_SPLIT, 1, 1><<<nProj, 64, 0, stream>>>(
        yn_h, yn_l, wq_h + wo, wq_l + wo, q_h, q_l, nullptr, nullptr, nullptr,
        nullptr, nullptr, 9, 128, 576, 576, 576, 576, 0, 0, 0, 0.f);
    gemmk<EP_SPLIT, 1, 1><<<nProj, 64, 0, stream>>>(
        xn_h, xn_l, wk_h + wo, wk_l + wo, k_h, k_l, nullptr, nullptr, nullptr,
        nullptr, nullptr, 9, 128, 576, 576, 576, 576, 0, 0, 0, 0.f);
    gemmk<EP_SPLIT_T, 1, 1><<<nProj, 64, 0, stream>>>(
        xn_h, xn_l, wv_h + wo, wv_l + wo, vt_h, vt_l, nullptr, nullptr, nullptr,
        nullptr, nullptr, 9, 128, 576, 576, 0, 576, 0, 0, 0, 0.f);
    // attn = sigmoid(q @ k^T * scale), per batch (XCD chunk ~ batch-major)
    gemmk<EP_SIG, 2, 1><<<nScore, 128, 0, stream>>>(
        q_h, q_l, k_h, k_l, attn_h, attn_l, nullptr, nullptr, nullptr, nullptr,
        nullptr, 8, 16, 576, 576, 1024, 576, 1024L * 576, 1024L * 576,
        1024L * 1024, scale);
    // o = attn @ vt^T, per batch (into yn buffers)
    gemmk<EP_SPLIT, 1, 1><<<nAV, 64, 0, stream>>>(
        attn_h, attn_l, vt_h, vt_l, yn_h, yn_l, nullptr, nullptr, nullptr,
        nullptr, nullptr, 9, 16, 1024, 1024, 576, 1024, 1024L * 1024,
        576L * 1024, 1024L * 576, 0.f);
    // t = o @ Wp^T + bp + xn  (fp32, into attn-aliased buffer)
    gemmk<EP_RES, 1, 1><<<nProj, 64, 0, stream>>>(
        yn_h, yn_l, wp_h + wo, wp_l + wo, nullptr, nullptr, t_f32, bp + z * 576,
        xn_h, xn_l, nullptr, 9, 128, 576, 576, 576, 576, 0, 0, 0, 0.f);
    // zn = LN(t) (into q buffers)
    ln576<<<8192, 576, 0, stream>>>(t_f32, lnz_g + z * 576, lnz_b + z * 576,
                                    q_h, q_l);
    // fused (+)= zn @ Wf[:, z*576:(z+1)*576]^T ; last z applies GELU into out
    if (z == 0)
      gemmk<EP_BIAS, 1, 1><<<nProj, 64, 0, stream>>>(
          q_h, q_l, wf_h + z * 576, wf_l + z * 576, nullptr, nullptr, fused, bf,
          nullptr, nullptr, nullptr, 9, 128, 576, 3456, 576, 576, 0, 0, 0, 0.f);
    else if (z < 5)
      gemmk<EP_ACC, 1, 1><<<nProj, 64, 0, stream>>>(
          q_h, q_l, wf_h + z * 576, wf_l + z * 576, nullptr, nullptr, fused,
          nullptr, nullptr, nullptr, nullptr, 9, 128, 576, 3456, 576, 576, 0, 0,
          0, 0.f);
    else
      gemmk<EP_ACCGELU, 1, 1><<<nProj, 64, 0, stream>>>(
          q_h, q_l, wf_h + z * 576, wf_l + z * 576, nullptr, nullptr, fused,
          nullptr, nullptr, nullptr, out, 9, 128, 576, 3456, 576, 576, 0, 0, 0,
          0.f);
  }
}

// Round 11
// 2008.385 us; speedup vs baseline: 1.1485x; 1.1485x over previous
//
#include <hip/hip_runtime.h>
#include <math.h>

#define LN_EPS 1e-5f

typedef short s8v __attribute__((ext_vector_type(8)));
typedef float f4v __attribute__((ext_vector_type(4)));

__device__ __forceinline__ short f2bf(float x) {
  union { float f; unsigned u; } v; v.f = x;
  const unsigned r = v.u + 0x7fffu + ((v.u >> 16) & 1u);
  return (short)(r >> 16);
}
__device__ __forceinline__ float bf2f(short s) {
  union { unsigned u; float f; } v;
  v.u = ((unsigned)(unsigned short)s) << 16;
  return v.f;
}

__device__ __forceinline__ void gld16(const void* g, void* l) {
  __builtin_amdgcn_global_load_lds(
      (const __attribute__((address_space(1))) void*)g,
      (__attribute__((address_space(3))) void*)l, 16, 0, 0);
}

enum { EP_SPLIT = 0, EP_SIG, EP_RES, EP_BIAS, EP_ACC, EP_ACCGELU };

// ---------------- R4-proven split-bf16 NT GEMM (BK=64) -------------------
// C = A * B^T, A[M][K], B[N][K], hi/lo bf16; 3-term MFMA ~= fp32.
// BM=128, BN=64*WC, BK=64, 2*WC waves (64x64 wave tile, 4x4 16x16x32 frags).
// XOR(row&7) chunk16 swizzle on global SOURCE (linear LDS dest) + same
// involution on ds_read -> conflict-free. 1D grid, XCD-bijective chunking,
// panel-major decode l -> pn, pm, zb.
template <int EP, int WC>
__global__ __launch_bounds__(128 * WC) void gemmk(
    const short* Ah, const short* Al, const short* Bh, const short* Bl,
    short* Ch, short* Cl, float* Cf, const float* bias, const short* resH,
    const short* resL, float* out2, int pnCnt, int pmCnt, int lda, int ldb,
    int ldc, int K, long sA, long sB, long sC, float scale) {
  constexpr int BM = 128, BN = 64 * WC, T = 128 * WC;
  constexpr int RA = (BM * 128) / (T * 16);
  constexpr int RB = (BN * 128) / (T * 16);
  __shared__ short lds[(2 * BM + 2 * BN) * 64];
  short* AsH = lds;
  short* AsL = lds + BM * 64;
  short* BsH = lds + 2 * BM * 64;
  short* BsL = lds + 2 * BM * 64 + BN * 64;

  const int tid = threadIdx.x;
  const int lane = tid & 63;
  const int wave = tid >> 6;
  const int wr = wave / WC;
  const int wc = wave % WC;
  const int half = lane >> 4;
  const int l15 = lane & 15;

  const int chunk = gridDim.x >> 3;
  const int l = ((int)blockIdx.x & 7) * chunk + ((int)blockIdx.x >> 3);
  const int pn = l % pnCnt;
  const int t1 = l / pnCnt;
  const int pm = t1 % pmCnt;
  const long zb = t1 / pmCnt;
  const int bm = pm * BM;
  const int bn = pn * BN;

  Ah += zb * sA; Al += zb * sA;
  Bh += zb * sB; Bl += zb * sB;

  f4v acc[4][4];
#pragma unroll
  for (int i = 0; i < 4; ++i)
#pragma unroll
    for (int j = 0; j < 4; ++j)
#pragma unroll
      for (int r = 0; r < 4; ++r) acc[i][j][r] = 0.f;

  for (int k0 = 0; k0 < K; k0 += 64) {
    __syncthreads();
#pragma unroll
    for (int t = 0; t < RA; ++t) {
      const int off = (t * T + tid) * 16;
      const int row = off >> 7;
      const int ke = ((((off >> 4) & 7) ^ (row & 7)) << 3);
      const long ga = (long)(bm + row) * lda + k0 + ke;
      gld16(Ah + ga, (char*)AsH + off);
      gld16(Al + ga, (char*)AsL + off);
    }
#pragma unroll
    for (int t = 0; t < RB; ++t) {
      const int off = (t * T + tid) * 16;
      const int row = off >> 7;
      const int ke = ((((off >> 4) & 7) ^ (row & 7)) << 3);
      const long gb = (long)(bn + row) * ldb + k0 + ke;
      gld16(Bh + gb, (char*)BsH + off);
      gld16(Bl + gb, (char*)BsL + off);
    }
    __syncthreads();

#pragma unroll
    for (int s = 0; s < 2; ++s) {
      s8v ah[4], al[4], bh[4], bl[4];
#pragma unroll
      for (int i = 0; i < 4; ++i) {
        const int r = wr * 64 + i * 16 + l15;
        const int ad = r * 64 + ((((s << 2) + half) ^ (r & 7)) << 3);
        ah[i] = *(const s8v*)&AsH[ad];
        al[i] = *(const s8v*)&AsL[ad];
      }
#pragma unroll
      for (int j = 0; j < 4; ++j) {
        const int c = wc * 64 + j * 16 + l15;
        const int bd = c * 64 + ((((s << 2) + half) ^ (c & 7)) << 3);
        bh[j] = *(const s8v*)&BsH[bd];
        bl[j] = *(const s8v*)&BsL[bd];
      }
#pragma unroll
      for (int i = 0; i < 4; ++i)
#pragma unroll
        for (int j = 0; j < 4; ++j) {
          acc[i][j] = __builtin_amdgcn_mfma_f32_16x16x32_bf16(ah[i], bh[j],
                                                              acc[i][j], 0, 0, 0);
          acc[i][j] = __builtin_amdgcn_mfma_f32_16x16x32_bf16(ah[i], bl[j],
                                                              acc[i][j], 0, 0, 0);
          acc[i][j] = __builtin_amdgcn_mfma_f32_16x16x32_bf16(al[i], bh[j],
                                                              acc[i][j], 0, 0, 0);
        }
    }
  }

  // Epilogue. D frag: col = lane&15, row = (lane>>4)*4 + reg (m89-verified).
#pragma unroll
  for (int i = 0; i < 4; ++i) {
#pragma unroll
    for (int r = 0; r < 4; ++r) {
      const int row = bm + wr * 64 + i * 16 + half * 4 + r;
#pragma unroll
      for (int j = 0; j < 4; ++j) {
        const int col = bn + wc * 64 + j * 16 + l15;
        float x = acc[i][j][r];
        if (EP == EP_SPLIT) {
          const long idx = zb * sC + (long)row * ldc + col;
          const short h = f2bf(x);
          Ch[idx] = h;
          Cl[idx] = f2bf(x - bf2f(h));
        } else if (EP == EP_SIG) {
          x = 1.f / (1.f + expf(-x * scale));
          const long idx = zb * sC + (long)row * ldc + col;
          const short h = f2bf(x);
          Ch[idx] = h;
          Cl[idx] = f2bf(x - bf2f(h));
        } else if (EP == EP_RES) {
          const long idx = (long)row * ldc + col;
          Cf[idx] = x + bias[col] + bf2f(resH[idx]) + bf2f(resL[idx]);
        } else if (EP == EP_BIAS) {
          const long idx = (long)row * ldc + col;
          Cf[idx] = x + bias[col];
        } else if (EP == EP_ACC) {
          const long idx = (long)row * ldc + col;
          Cf[idx] += x;
        } else if (EP == EP_ACCGELU) {
          const long idx = (long)row * ldc + col;
          const float sum = Cf[idx] + x;
          out2[idx] = 0.5f * sum * (1.f + erff(sum * 0.70710678118654752f));
        }
      }
    }
  }
}

// ---------------- fused q/k/vt projection (BK=32, hi/lo interleaved) -----
// One launch computes q = yn@Wq^T, k = xn@Wk^T, vt = (xn@Wv^T)^T.
// 27 column-blocks: pn<9 -> q, pn<18 -> k, else vt (per-block uniform select).
// BK=32: LDS rows stay 128B by packing hi (logical chunks 0-3, k=chunk*8) and
// lo (chunks 4-7) of the SAME row; physical slot = chunk ^ (row&7) -> the
// proven XOR-8 swizzle is unchanged (lo slot = hi slot ^ 4). LDS = 24KB/block
// -> 6 blocks/CU; launch_bounds(128,4) pins VGPR<=128 -> 16-wave/CU cap.
__global__ __launch_bounds__(128, 4) void proj3k(
    const short* ynh, const short* ynl, const short* xnh, const short* xnl,
    const short* wqh, const short* wql, const short* wkh, const short* wkl,
    const short* wvh, const short* wvl, short* qh, short* ql, short* kh,
    short* kl, short* vth, short* vtl) {
  constexpr int T = 128, RA = 8, RB = 4;
  __shared__ short As[128 * 64];  // [row][8 slots x 8 shorts]
  __shared__ short Bs[64 * 64];

  const int tid = threadIdx.x;
  const int lane = tid & 63;
  const int wr = tid >> 6;  // 0..1
  const int half = lane >> 4;
  const int l15 = lane & 15;

  const int chunk = gridDim.x >> 3;
  const int l = ((int)blockIdx.x & 7) * chunk + ((int)blockIdx.x >> 3);
  const int pn = l % 27;
  const int pm = l / 27;
  const int sel = pn / 9;  // 0=q 1=k 2=v (uniform per block)
  const int bm = pm * 128;
  const int bn = (pn - sel * 9) * 64;  // local col base within one projection

  const short* Ah = sel ? xnh : ynh;
  const short* Al = sel ? xnl : ynl;
  const short* Bh = sel == 0 ? wqh : (sel == 1 ? wkh : wvh);
  const short* Bl = sel == 0 ? wql : (sel == 1 ? wkl : wvl);

  f4v acc[4][4];
#pragma unroll
  for (int i = 0; i < 4; ++i)
#pragma unroll
    for (int j = 0; j < 4; ++j)
#pragma unroll
      for (int r = 0; r < 4; ++r) acc[i][j][r] = 0.f;

  for (int k0 = 0; k0 < 576; k0 += 32) {
    __syncthreads();
#pragma unroll
    for (int t = 0; t < RA; ++t) {
      const int off = (t * T + tid) * 16;
      const int row = off >> 7;
      const int c = ((off >> 4) & 7) ^ (row & 7);  // logical chunk
      const short* src = (c & 4) ? Al : Ah;
      gld16(src + (long)(bm + row) * 576 + k0 + ((c & 3) << 3),
            (char*)As + off);
    }
#pragma unroll
    for (int t = 0; t < RB; ++t) {
      const int off = (t * T + tid) * 16;
      const int row = off >> 7;
      const int c = ((off >> 4) & 7) ^ (row & 7);
      const short* src = (c & 4) ? Bl : Bh;
      gld16(src + (long)(bn + row) * 576 + k0 + ((c & 3) << 3),
            (char*)Bs + off);
    }
    __syncthreads();

    s8v ah[4], al[4], bh[4], bl[4];
#pragma unroll
    for (int i = 0; i < 4; ++i) {
      const int r = wr * 64 + i * 16 + l15;
      const int s0 = r * 64 + ((half ^ (r & 7)) << 3);
      ah[i] = *(const s8v*)&As[s0];
      al[i] = *(const s8v*)&As[s0 ^ 32];  // lo slot = hi slot ^ 4
    }
#pragma unroll
    for (int j = 0; j < 4; ++j) {
      const int c2 = j * 16 + l15;
      const int s0 = c2 * 64 + ((half ^ (c2 & 7)) << 3);
      bh[j] = *(const s8v*)&Bs[s0];
      bl[j] = *(const s8v*)&Bs[s0 ^ 32];
    }
#pragma unroll
    for (int i = 0; i < 4; ++i)
#pragma unroll
      for (int j = 0; j < 4; ++j) {
        acc[i][j] = __builtin_amdgcn_mfma_f32_16x16x32_bf16(ah[i], bh[j],
                                                            acc[i][j], 0, 0, 0);
        acc[i][j] = __builtin_amdgcn_mfma_f32_16x16x32_bf16(ah[i], bl[j],
                                                            acc[i][j], 0, 0, 0);
        acc[i][j] = __builtin_amdgcn_mfma_f32_16x16x32_bf16(al[i], bh[j],
                                                            acc[i][j], 0, 0, 0);
      }
  }

#pragma unroll
  for (int i = 0; i < 4; ++i) {
#pragma unroll
    for (int r = 0; r < 4; ++r) {
      const int row = bm + wr * 64 + i * 16 + half * 4 + r;
#pragma unroll
      for (int j = 0; j < 4; ++j) {
        const int col = bn + j * 16 + l15;
        const float x = acc[i][j][r];
        const short h = f2bf(x);
        const short lo = f2bf(x - bf2f(h));
        if (sel == 2) {  // vt[b][col][tok], row = b*1024+tok
          const long idx = ((long)(row >> 10) * 576 + col) * 1024 + (row & 1023);
          vth[idx] = h;
          vtl[idx] = lo;
        } else {
          const long idx = (long)row * 576 + col;
          short* oh = sel ? kh : qh;
          short* ol = sel ? kl : ql;
          oh[idx] = h;
          ol[idx] = lo;
        }
      }
    }
  }
}

// LayerNorm over C=576, writes hi/lo bf16 split. One 576-thread block per row.
__global__ __launch_bounds__(576) void ln576(const float* __restrict__ x,
                                             const float* __restrict__ g,
                                             const float* __restrict__ b,
                                             short* __restrict__ oh,
                                             short* __restrict__ ol) {
  __shared__ float red[2][9];
  __shared__ float mu_s, rs_s;
  const long row = blockIdx.x;
  const int t = threadIdx.x;
  const float v = x[row * 576 + t];
  float s = v, s2 = v * v;
#pragma unroll
  for (int off = 32; off > 0; off >>= 1) {
    s += __shfl_xor(s, off);
    s2 += __shfl_xor(s2, off);
  }
  if ((t & 63) == 0) {
    red[0][t >> 6] = s;
    red[1][t >> 6] = s2;
  }
  __syncthreads();
  if (t == 0) {
    float a = 0.f, a2 = 0.f;
#pragma unroll
    for (int i = 0; i < 9; ++i) {
      a += red[0][i];
      a2 += red[1][i];
    }
    const float mu = a * (1.f / 576.f);
    mu_s = mu;
    rs_s = rsqrtf(a2 * (1.f / 576.f) - mu * mu + LN_EPS);
  }
  __syncthreads();
  const float y = (v - mu_s) * rs_s * g[t] + b[t];
  const short h = f2bf(y);
  oh[row * 576 + t] = h;
  ol[row * 576 + t] = f2bf(y - bf2f(h));
}

// fp32 -> (hi,lo) bf16 split, elementwise.
__global__ __launch_bounds__(256) void splitk(const float* __restrict__ in,
                                              short* __restrict__ oh,
                                              short* __restrict__ ol, long n) {
  long i = (long)blockIdx.x * blockDim.x + threadIdx.x;
  const long stride = (long)gridDim.x * blockDim.x;
  for (; i < n; i += stride) {
    const float x = in[i];
    const short h = f2bf(x);
    oh[i] = h;
    ol[i] = f2bf(x - bf2f(h));
  }
}

extern "C" void kernel_launch(void* const* d_in, const int* in_sizes, int n_in,
                              void* d_out, int out_size, void* d_ws,
                              size_t ws_size, hipStream_t stream) {
  const float* img = (const float*)d_in[0];
  const float* aolp = (const float*)d_in[1];
  const float* dolp = (const float*)d_in[2];
  const float* lnx_g = (const float*)d_in[3];
  const float* lnx_b = (const float*)d_in[4];
  const float* lny_g = (const float*)d_in[5];
  const float* lny_b = (const float*)d_in[6];
  const float* lnz_g = (const float*)d_in[7];
  const float* lnz_b = (const float*)d_in[8];
  const float* Wq = (const float*)d_in[9];
  const float* Wk = (const float*)d_in[10];
  const float* Wv = (const float*)d_in[11];
  const float* Wp = (const float*)d_in[12];
  const float* bp = (const float*)d_in[13];
  const float* Wf = (const float*)d_in[14];
  const float* bf = (const float*)d_in[15];
  float* out = (float*)d_out;

  const long S = 8L * 1024 * 576;   // 4,718,592
  const long W = 6L * 576 * 576;    // 1,990,656 (== 576*3456)
  char* p = (char*)d_ws;
  auto alloc = [&](long bytes) {
    char* r = p;
    p += (bytes + 255) & ~255L;
    return r;
  };
  short* xn_h = (short*)alloc(S * 2);
  short* xn_l = (short*)alloc(S * 2);
  short* yn_h = (short*)alloc(S * 2);  // also o after AV
  short* yn_l = (short*)alloc(S * 2);
  short* q_h = (short*)alloc(S * 2);   // also z after LNz
  short* q_l = (short*)alloc(S * 2);
  short* k_h = (short*)alloc(S * 2);
  short* k_l = (short*)alloc(S * 2);
  short* vt_h = (short*)alloc(S * 2);  // [8][576][1024]
  short* vt_l = (short*)alloc(S * 2);
  short* attn_h = (short*)alloc(8L * 1024 * 1024 * 2 * 2);  // hi then lo
  short* attn_l = attn_h + 8L * 1024 * 1024;
  float* t_f32 = (float*)attn_h;  // aliases attn (dead after AV)
  float* fused = (float*)alloc(S * 4);
  short* wq_h = (short*)alloc(W * 2);
  short* wq_l = (short*)alloc(W * 2);
  short* wk_h = (short*)alloc(W * 2);
  short* wk_l = (short*)alloc(W * 2);
  short* wv_h = (short*)alloc(W * 2);
  short* wv_l = (short*)alloc(W * 2);
  short* wp_h = (short*)alloc(W * 2);
  short* wp_l = (short*)alloc(W * 2);
  short* wf_h = (short*)alloc(W * 2);
  short* wf_l = (short*)alloc(W * 2);

  splitk<<<1024, 256, 0, stream>>>(Wq, wq_h, wq_l, W);
  splitk<<<1024, 256, 0, stream>>>(Wk, wk_h, wk_l, W);
  splitk<<<1024, 256, 0, stream>>>(Wv, wv_h, wv_l, W);
  splitk<<<1024, 256, 0, stream>>>(Wp, wp_h, wp_l, W);
  splitk<<<1024, 256, 0, stream>>>(Wf, wf_h, wf_l, W);

  const float* src[3] = {img, aolp, dolp};
  const int xi[6] = {0, 0, 1, 1, 2, 2};
  const int yi[6] = {1, 2, 0, 2, 0, 1};
  const float scale = 1.f / 24.f;  // 576^-0.5

  const int nProj3 = 27 * 64;    // 1728 blocks (%8==0)
  const int nScore = 8 * 8 * 8;  // 512
  const int nAV = 9 * 8 * 8;     // 576
  const int nN = 9 * 64;         // 576

  for (int z = 0; z < 6; ++z) {
    const long wo = (long)z * 576 * 576;
    ln576<<<8192, 576, 0, stream>>>(src[xi[z]], lnx_g + z * 576,
                                    lnx_b + z * 576, xn_h, xn_l);
    ln576<<<8192, 576, 0, stream>>>(src[yi[z]], lny_g + z * 576,
                                    lny_b + z * 576, yn_h, yn_l);
    // fused q/k/vt projection (one launch, 1728 blocks)
    proj3k<<<nProj3, 128, 0, stream>>>(
        yn_h, yn_l, xn_h, xn_l, wq_h + wo, wq_l + wo, wk_h + wo, wk_l + wo,
        wv_h + wo, wv_l + wo, q_h, q_l, k_h, k_l, vt_h, vt_l);
    // attn = sigmoid(q @ k^T * scale), per batch
    gemmk<EP_SIG, 2><<<nScore, 256, 0, stream>>>(
        q_h, q_l, k_h, k_l, attn_h, attn_l, nullptr, nullptr, nullptr, nullptr,
        nullptr, 8, 8, 576, 576, 1024, 576, 1024L * 576, 1024L * 576,
        1024L * 1024, scale);
    // o = attn @ vt^T, per batch (into yn buffers)
    gemmk<EP_SPLIT, 1><<<nAV, 128, 0, stream>>>(
        attn_h, attn_l, vt_h, vt_l, yn_h, yn_l, nullptr, nullptr, nullptr,
        nullptr, nullptr, 9, 8, 1024, 1024, 576, 1024, 1024L * 1024,
        576L * 1024, 1024L * 576, 0.f);
    // t = o @ Wp^T + bp + xn  (fp32, into attn-aliased buffer)
    gemmk<EP_RES, 1><<<nN, 128, 0, stream>>>(
        yn_h, yn_l, wp_h + wo, wp_l + wo, nullptr, nullptr, t_f32, bp + z * 576,
        xn_h, xn_l, nullptr, 9, 64, 576, 576, 576, 576, 0, 0, 0, 0.f);
    // zn = LN(t) (into q buffers)
    ln576<<<8192, 576, 0, stream>>>(t_f32, lnz_g + z * 576, lnz_b + z * 576,
                                    q_h, q_l);
    // fused (+)= zn @ Wf[:, z*576:(z+1)*576]^T ; last z applies GELU into out
    if (z == 0)
      gemmk<EP_BIAS, 1><<<nN, 128, 0, stream>>>(
          q_h, q_l, wf_h + z * 576, wf_l + z * 576, nullptr, nullptr, fused, bf,
          nullptr, nullptr, nullptr, 9, 64, 576, 3456, 576, 576, 0, 0, 0, 0.f);
    else if (z < 5)
      gemmk<EP_ACC, 1><<<nN, 128, 0, stream>>>(
          q_h, q_l, wf_h + z * 576, wf_l + z * 576, nullptr, nullptr, fused,
          nullptr, nullptr, nullptr, nullptr, 9, 64, 576, 3456, 576, 576, 0, 0,
          0, 0.f);
    else
      gemmk<EP_ACCGELU, 1><<<nN, 128, 0, stream>>>(
          q_h, q_l, wf_h + z * 576, wf_l + z * 576, nullptr, nullptr, fused,
          nullptr, nullptr, nullptr, out, 9, 64, 576, 3456, 576, 576, 0, 0, 0,
          0.f);
  }
}

// Round 14
// 1894.822 us; speedup vs baseline: 1.2174x; 1.0599x over previous
//
#include <hip/hip_runtime.h>
#include <math.h>

#define LN_EPS 1e-5f

typedef short s8v __attribute__((ext_vector_type(8)));
typedef float f4v __attribute__((ext_vector_type(4)));

__device__ __forceinline__ short f2bf(float x) {
  union { float f; unsigned u; } v; v.f = x;
  const unsigned r = v.u + 0x7fffu + ((v.u >> 16) & 1u);
  return (short)(r >> 16);
}
__device__ __forceinline__ float bf2f(short s) {
  union { unsigned u; float f; } v;
  v.u = ((unsigned)(unsigned short)s) << 16;
  return v.f;
}

__device__ __forceinline__ void gld16(const void* g, void* l) {
  __builtin_amdgcn_global_load_lds(
      (const __attribute__((address_space(1))) void*)g,
      (__attribute__((address_space(3))) void*)l, 16, 0, 0);
}

enum { EP_SPLIT = 0, EP_SIG, EP_RES, EP_BIAS, EP_ACC, EP_ACCGELU };

// ---- split-bf16 NT GEMM, BK=32 hi/lo-interleaved rows, 2-phase dbuf ----
// C = A * B^T; A[M][K], B[N][K] as hi/lo bf16; 3-term MFMA ~= fp32.
// BM=128, BN=64*WC, 2*WC waves, 64x64 wave tile (4x4 frags of 16x16x32).
// LDS row = 128B: logical chunks 0-3 = hi k-chunks (k=c*8), 4-7 = lo;
// physical slot = chunk ^ (row&7) (R11-validated swizzle; lo = hi ^ 32 shorts).
// 2-phase: STAGE(next) issued BEFORE compute(cur); ONE __syncthreads()/step
// (its implicit vmcnt(0) drain waits only the residual after compute).
// 1D grid, XCD-bijective chunking (nwg%8==0), panel-major decode.
template <int EP, int WC>
__global__ __launch_bounds__(128 * WC) void gemmk(
    const short* Ah, const short* Al, const short* Bh, const short* Bl,
    short* Ch, short* Cl, float* Cf, const float* bias, const short* resH,
    const short* resL, float* out2, int pnCnt, int pmCnt, int lda, int ldb,
    int ldc, int K, long sA, long sB, long sC, float scale) {
  constexpr int BM = 128, BN = 64 * WC, T = 128 * WC;
  constexpr int RA = (BM * 128) / (T * 16);
  constexpr int RB = (BN * 128) / (T * 16);
  __shared__ short lds[2][(BM + BN) * 64];

  const int tid = threadIdx.x;
  const int lane = tid & 63;
  const int wave = tid >> 6;
  const int wr = wave / WC;
  const int wc = wave % WC;
  const int half = lane >> 4;
  const int l15 = lane & 15;

  const int chunk = gridDim.x >> 3;
  const int l = ((int)blockIdx.x & 7) * chunk + ((int)blockIdx.x >> 3);
  const int pn = l % pnCnt;
  const int t1 = l / pnCnt;
  const int pm = t1 % pmCnt;
  const long zb = t1 / pmCnt;
  const int bm = pm * BM;
  const int bn = pn * BN;

  Ah += zb * sA; Al += zb * sA;
  Bh += zb * sB; Bl += zb * sB;

  auto STAGE = [&](int b, int k0) {
    short* As = lds[b];
    short* Bs = lds[b] + BM * 64;
#pragma unroll
    for (int t = 0; t < RA; ++t) {
      const int off = (t * T + tid) * 16;
      const int row = off >> 7;
      const int c = ((off >> 4) & 7) ^ (row & 7);
      const short* src = (c & 4) ? Al : Ah;
      gld16(src + (long)(bm + row) * lda + k0 + ((c & 3) << 3),
            (char*)As + off);
    }
#pragma unroll
    for (int t = 0; t < RB; ++t) {
      const int off = (t * T + tid) * 16;
      const int row = off >> 7;
      const int c = ((off >> 4) & 7) ^ (row & 7);
      const short* src = (c & 4) ? Bl : Bh;
      gld16(src + (long)(bn + row) * ldb + k0 + ((c & 3) << 3),
            (char*)Bs + off);
    }
  };

  f4v acc[4][4];
#pragma unroll
  for (int i = 0; i < 4; ++i)
#pragma unroll
    for (int j = 0; j < 4; ++j)
#pragma unroll
      for (int r = 0; r < 4; ++r) acc[i][j][r] = 0.f;

  STAGE(0, 0);
  __syncthreads();
  int cur = 0;
  const int nt = K >> 5;
  for (int t = 0; t < nt; ++t) {
    if (t + 1 < nt) STAGE(cur ^ 1, (t + 1) << 5);
    const short* As = lds[cur];
    const short* Bs = lds[cur] + BM * 64;
    s8v ah[4], al[4], bh[4], bl[4];
#pragma unroll
    for (int i = 0; i < 4; ++i) {
      const int r = wr * 64 + i * 16 + l15;
      const int s0 = r * 64 + ((half ^ (r & 7)) << 3);
      ah[i] = *(const s8v*)&As[s0];
      al[i] = *(const s8v*)&As[s0 ^ 32];
    }
#pragma unroll
    for (int j = 0; j < 4; ++j) {
      const int c2 = wc * 64 + j * 16 + l15;
      const int s0 = c2 * 64 + ((half ^ (c2 & 7)) << 3);
      bh[j] = *(const s8v*)&Bs[s0];
      bl[j] = *(const s8v*)&Bs[s0 ^ 32];
    }
#pragma unroll
    for (int i = 0; i < 4; ++i)
#pragma unroll
      for (int j = 0; j < 4; ++j) {
        acc[i][j] = __builtin_amdgcn_mfma_f32_16x16x32_bf16(ah[i], bh[j],
                                                            acc[i][j], 0, 0, 0);
        acc[i][j] = __builtin_amdgcn_mfma_f32_16x16x32_bf16(ah[i], bl[j],
                                                            acc[i][j], 0, 0, 0);
        acc[i][j] = __builtin_amdgcn_mfma_f32_16x16x32_bf16(al[i], bh[j],
                                                            acc[i][j], 0, 0, 0);
      }
    __syncthreads();
    cur ^= 1;
  }

  // Epilogue. D frag: col = lane&15, row = (lane>>4)*4 + reg (m89-verified).
#pragma unroll
  for (int i = 0; i < 4; ++i) {
#pragma unroll
    for (int r = 0; r < 4; ++r) {
      const int row = bm + wr * 64 + i * 16 + half * 4 + r;
#pragma unroll
      for (int j = 0; j < 4; ++j) {
        const int col = bn + wc * 64 + j * 16 + l15;
        float x = acc[i][j][r];
        if (EP == EP_SPLIT) {
          const long idx = zb * sC + (long)row * ldc + col;
          const short h = f2bf(x);
          Ch[idx] = h;
          Cl[idx] = f2bf(x - bf2f(h));
        } else if (EP == EP_SIG) {
          x = 1.f / (1.f + expf(-x * scale));
          const long idx = zb * sC + (long)row * ldc + col;
          const short h = f2bf(x);
          Ch[idx] = h;
          Cl[idx] = f2bf(x - bf2f(h));
        } else if (EP == EP_RES) {
          const long idx = (long)row * ldc + col;
          Cf[idx] = x + bias[col] + bf2f(resH[idx]) + bf2f(resL[idx]);
        } else if (EP == EP_BIAS) {
          const long idx = (long)row * ldc + col;
          Cf[idx] = x + bias[col];
        } else if (EP == EP_ACC) {
          const long idx = (long)row * ldc + col;
          Cf[idx] += x;
        } else if (EP == EP_ACCGELU) {
          const long idx = (long)row * ldc + col;
          const float sum = Cf[idx] + x;
          out2[idx] = 0.5f * sum * (1.f + erff(sum * 0.70710678118654752f));
        }
      }
    }
  }
}

// ---- fused q/k/vt projection, BK=32 interleaved, 2-phase dbuf ----
// 27 column-blocks: pn<9 -> q (A=yn), pn<18 -> k (A=xn), else vt (A=xn,
// transposed store). Same pipeline/swizzle as gemmk.
__global__ __launch_bounds__(128) void proj3k(
    const short* ynh, const short* ynl, const short* xnh, const short* xnl,
    const short* wqh, const short* wql, const short* wkh, const short* wkl,
    const short* wvh, const short* wvl, short* qh, short* ql, short* kh,
    short* kl, short* vth, short* vtl) {
  constexpr int T = 128, RA = 8, RB = 4;
  __shared__ short lds[2][(128 + 64) * 64];

  const int tid = threadIdx.x;
  const int lane = tid & 63;
  const int wr = tid >> 6;
  const int half = lane >> 4;
  const int l15 = lane & 15;

  const int chunk = gridDim.x >> 3;
  const int l = ((int)blockIdx.x & 7) * chunk + ((int)blockIdx.x >> 3);
  const int pn = l % 27;
  const int pm = l / 27;
  const int sel = pn / 9;  // 0=q 1=k 2=v (uniform per block)
  const int bm = pm * 128;
  const int bn = (pn - sel * 9) * 64;

  const short* Ah = sel ? xnh : ynh;
  const short* Al = sel ? xnl : ynl;
  const short* Bh = sel == 0 ? wqh : (sel == 1 ? wkh : wvh);
  const short* Bl = sel == 0 ? wql : (sel == 1 ? wkl : wvl);

  auto STAGE = [&](int b, int k0) {
    short* As = lds[b];
    short* Bs = lds[b] + 128 * 64;
#pragma unroll
    for (int t = 0; t < RA; ++t) {
      const int off = (t * T + tid) * 16;
      const int row = off >> 7;
      const int c = ((off >> 4) & 7) ^ (row & 7);
      const short* src = (c & 4) ? Al : Ah;
      gld16(src + (long)(bm + row) * 576 + k0 + ((c & 3) << 3),
            (char*)As + off);
    }
#pragma unroll
    for (int t = 0; t < RB; ++t) {
      const int off = (t * T + tid) * 16;
      const int row = off >> 7;
      const int c = ((off >> 4) & 7) ^ (row & 7);
      const short* src = (c & 4) ? Bl : Bh;
      gld16(src + (long)(bn + row) * 576 + k0 + ((c & 3) << 3),
            (char*)Bs + off);
    }
  };

  f4v acc[4][4];
#pragma unroll
  for (int i = 0; i < 4; ++i)
#pragma unroll
    for (int j = 0; j < 4; ++j)
#pragma unroll
      for (int r = 0; r < 4; ++r) acc[i][j][r] = 0.f;

  STAGE(0, 0);
  __syncthreads();
  int cur = 0;
  for (int t = 0; t < 18; ++t) {
    if (t + 1 < 18) STAGE(cur ^ 1, (t + 1) << 5);
    const short* As = lds[cur];
    const short* Bs = lds[cur] + 128 * 64;
    s8v ah[4], al[4], bh[4], bl[4];
#pragma unroll
    for (int i = 0; i < 4; ++i) {
      const int r = wr * 64 + i * 16 + l15;
      const int s0 = r * 64 + ((half ^ (r & 7)) << 3);
      ah[i] = *(const s8v*)&As[s0];
      al[i] = *(const s8v*)&As[s0 ^ 32];
    }
#pragma unroll
    for (int j = 0; j < 4; ++j) {
      const int c2 = j * 16 + l15;
      const int s0 = c2 * 64 + ((half ^ (c2 & 7)) << 3);
      bh[j] = *(const s8v*)&Bs[s0];
      bl[j] = *(const s8v*)&Bs[s0 ^ 32];
    }
#pragma unroll
    for (int i = 0; i < 4; ++i)
#pragma unroll
      for (int j = 0; j < 4; ++j) {
        acc[i][j] = __builtin_amdgcn_mfma_f32_16x16x32_bf16(ah[i], bh[j],
                                                            acc[i][j], 0, 0, 0);
        acc[i][j] = __builtin_amdgcn_mfma_f32_16x16x32_bf16(ah[i], bl[j],
                                                            acc[i][j], 0, 0, 0);
        acc[i][j] = __builtin_amdgcn_mfma_f32_16x16x32_bf16(al[i], bh[j],
                                                            acc[i][j], 0, 0, 0);
      }
    __syncthreads();
    cur ^= 1;
  }

#pragma unroll
  for (int i = 0; i < 4; ++i) {
#pragma unroll
    for (int r = 0; r < 4; ++r) {
      const int row = bm + wr * 64 + i * 16 + half * 4 + r;
#pragma unroll
      for (int j = 0; j < 4; ++j) {
        const int col = bn + j * 16 + l15;
        const float x = acc[i][j][r];
        const short h = f2bf(x);
        const short lo = f2bf(x - bf2f(h));
        if (sel == 2) {  // vt[b][col][tok], row = b*1024+tok
          const long idx = ((long)(row >> 10) * 576 + col) * 1024 + (row & 1023);
          vth[idx] = h;
          vtl[idx] = lo;
        } else {
          const long idx = (long)row * 576 + col;
          short* oh = sel ? kh : qh;
          short* ol = sel ? kl : ql;
          oh[idx] = h;
          ol[idx] = lo;
        }
      }
    }
  }
}

// LayerNorm over C=576, writes hi/lo bf16 split. One 576-thread block per row.
__global__ __launch_bounds__(576) void ln576(const float* __restrict__ x,
                                             const float* __restrict__ g,
                                             const float* __restrict__ b,
                                             short* __restrict__ oh,
                                             short* __restrict__ ol) {
  __shared__ float red[2][9];
  __shared__ float mu_s, rs_s;
  const long row = blockIdx.x;
  const int t = threadIdx.x;
  const float v = x[row * 576 + t];
  float s = v, s2 = v * v;
#pragma unroll
  for (int off = 32; off > 0; off >>= 1) {
    s += __shfl_xor(s, off);
    s2 += __shfl_xor(s2, off);
  }
  if ((t & 63) == 0) {
    red[0][t >> 6] = s;
    red[1][t >> 6] = s2;
  }
  __syncthreads();
  if (t == 0) {
    float a = 0.f, a2 = 0.f;
#pragma unroll
    for (int i = 0; i < 9; ++i) {
      a += red[0][i];
      a2 += red[1][i];
    }
    const float mu = a * (1.f / 576.f);
    mu_s = mu;
    rs_s = rsqrtf(a2 * (1.f / 576.f) - mu * mu + LN_EPS);
  }
  __syncthreads();
  const float y = (v - mu_s) * rs_s * g[t] + b[t];
  const short h = f2bf(y);
  oh[row * 576 + t] = h;
  ol[row * 576 + t] = f2bf(y - bf2f(h));
}

// fp32 -> (hi,lo) bf16 split, elementwise.
__global__ __launch_bounds__(256) void splitk(const float* __restrict__ in,
                                              short* __restrict__ oh,
                                              short* __restrict__ ol, long n) {
  long i = (long)blockIdx.x * blockDim.x + threadIdx.x;
  const long stride = (long)gridDim.x * blockDim.x;
  for (; i < n; i += stride) {
    const float x = in[i];
    const short h = f2bf(x);
    oh[i] = h;
    ol[i] = f2bf(x - bf2f(h));
  }
}

extern "C" void kernel_launch(void* const* d_in, const int* in_sizes, int n_in,
                              void* d_out, int out_size, void* d_ws,
                              size_t ws_size, hipStream_t stream) {
  const float* img = (const float*)d_in[0];
  const float* aolp = (const float*)d_in[1];
  const float* dolp = (const float*)d_in[2];
  const float* lnx_g = (const float*)d_in[3];
  const float* lnx_b = (const float*)d_in[4];
  const float* lny_g = (const float*)d_in[5];
  const float* lny_b = (const float*)d_in[6];
  const float* lnz_g = (const float*)d_in[7];
  const float* lnz_b = (const float*)d_in[8];
  const float* Wq = (const float*)d_in[9];
  const float* Wk = (const float*)d_in[10];
  const float* Wv = (const float*)d_in[11];
  const float* Wp = (const float*)d_in[12];
  const float* bp = (const float*)d_in[13];
  const float* Wf = (const float*)d_in[14];
  const float* bf = (const float*)d_in[15];
  float* out = (float*)d_out;

  const long S = 8L * 1024 * 576;   // 4,718,592
  const long W = 6L * 576 * 576;    // 1,990,656 (== 576*3456)
  char* p = (char*)d_ws;
  auto alloc = [&](long bytes) {
    char* r = p;
    p += (bytes + 255) & ~255L;
    return r;
  };
  short* xn_h = (short*)alloc(S * 2);
  short* xn_l = (short*)alloc(S * 2);
  short* yn_h = (short*)alloc(S * 2);  // also o after AV
  short* yn_l = (short*)alloc(S * 2);
  short* q_h = (short*)alloc(S * 2);   // also z after LNz
  short* q_l = (short*)alloc(S * 2);
  short* k_h = (short*)alloc(S * 2);
  short* k_l = (short*)alloc(S * 2);
  short* vt_h = (short*)alloc(S * 2);  // [8][576][1024]
  short* vt_l = (short*)alloc(S * 2);
  short* attn_h = (short*)alloc(8L * 1024 * 1024 * 2 * 2);  // hi then lo
  short* attn_l = attn_h + 8L * 1024 * 1024;
  float* t_f32 = (float*)attn_h;  // aliases attn (dead after AV)
  float* fused = (float*)alloc(S * 4);
  short* wq_h = (short*)alloc(W * 2);
  short* wq_l = (short*)alloc(W * 2);
  short* wk_h = (short*)alloc(W * 2);
  short* wk_l = (short*)alloc(W * 2);
  short* wv_h = (short*)alloc(W * 2);
  short* wv_l = (short*)alloc(W * 2);
  short* wp_h = (short*)alloc(W * 2);
  short* wp_l = (short*)alloc(W * 2);
  short* wf_h = (short*)alloc(W * 2);
  short* wf_l = (short*)alloc(W * 2);

  splitk<<<1024, 256, 0, stream>>>(Wq, wq_h, wq_l, W);
  splitk<<<1024, 256, 0, stream>>>(Wk, wk_h, wk_l, W);
  splitk<<<1024, 256, 0, stream>>>(Wv, wv_h, wv_l, W);
  splitk<<<1024, 256, 0, stream>>>(Wp, wp_h, wp_l, W);
  splitk<<<1024, 256, 0, stream>>>(Wf, wf_h, wf_l, W);

  const float* src[3] = {img, aolp, dolp};
  const int xi[6] = {0, 0, 1, 1, 2, 2};
  const int yi[6] = {1, 2, 0, 2, 0, 1};
  const float scale = 1.f / 24.f;  // 576^-0.5

  const int nProj3 = 27 * 64;    // 1728 blocks (%8==0)
  const int nScore = 8 * 8 * 8;  // 512
  const int nAV = 9 * 8 * 8;     // 576
  const int nN = 9 * 64;         // 576

  for (int z = 0; z < 6; ++z) {
    const long wo = (long)z * 576 * 576;
    ln576<<<8192, 576, 0, stream>>>(src[xi[z]], lnx_g + z * 576,
                                    lnx_b + z * 576, xn_h, xn_l);
    ln576<<<8192, 576, 0, stream>>>(src[yi[z]], lny_g + z * 576,
                                    lny_b + z * 576, yn_h, yn_l);
    // fused q/k/vt projection (one launch, 1728 blocks)
    proj3k<<<nProj3, 128, 0, stream>>>(
        yn_h, yn_l, xn_h, xn_l, wq_h + wo, wq_l + wo, wk_h + wo, wk_l + wo,
        wv_h + wo, wv_l + wo, q_h, q_l, k_h, k_l, vt_h, vt_l);
    // attn = sigmoid(q @ k^T * scale), per batch
    gemmk<EP_SIG, 2><<<nScore, 256, 0, stream>>>(
        q_h, q_l, k_h, k_l, attn_h, attn_l, nullptr, nullptr, nullptr, nullptr,
        nullptr, 8, 8, 576, 576, 1024, 576, 1024L * 576, 1024L * 576,
        1024L * 1024, scale);
    // o = attn @ vt^T, per batch (into yn buffers)
    gemmk<EP_SPLIT, 1><<<nAV, 128, 0, stream>>>(
        attn_h, attn_l, vt_h, vt_l, yn_h, yn_l, nullptr, nullptr, nullptr,
        nullptr, nullptr, 9, 8, 1024, 1024, 576, 1024, 1024L * 1024,
        576L * 1024, 1024L * 576, 0.f);
    // t = o @ Wp^T + bp + xn  (fp32, into attn-aliased buffer)
    gemmk<EP_RES, 1><<<nN, 128, 0, stream>>>(
        yn_h, yn_l, wp_h + wo, wp_l + wo, nullptr, nullptr, t_f32, bp + z * 576,
        xn_h, xn_l, nullptr, 9, 64, 576, 576, 576, 576, 0, 0, 0, 0.f);
    // zn = LN(t) (into q buffers)
    ln576<<<8192, 576, 0, stream>>>(t_f32, lnz_g + z * 576, lnz_b + z * 576,
                                    q_h, q_l);
    // fused (+)= zn @ Wf[:, z*576:(z+1)*576]^T ; last z applies GELU into out
    if (z == 0)
      gemmk<EP_BIAS, 1><<<nN, 128, 0, stream>>>(
          q_h, q_l, wf_h + z * 576, wf_l + z * 576, nullptr, nullptr, fused, bf,
          nullptr, nullptr, nullptr, 9, 64, 576, 3456, 576, 576, 0, 0, 0, 0.f);
    else if (z < 5)
      gemmk<EP_ACC, 1><<<nN, 128, 0, stream>>>(
          q_h, q_l, wf_h + z * 576, wf_l + z * 576, nullptr, nullptr, fused,
          nullptr, nullptr, nullptr, nullptr, 9, 64, 576, 3456, 576, 576, 0, 0,
          0, 0.f);
    else
      gemmk<EP_ACCGELU, 1><<<nN, 128, 0, stream>>>(
          q_h, q_l, wf_h + z * 576, wf_l + z * 576, nullptr, nullptr, fused,
          nullptr, nullptr, nullptr, out, 9, 64, 576, 3456, 576, 576, 0, 0, 0,
          0.f);
  }
}